// Round 5
// baseline (422.545 us; speedup 1.0000x reference)
//
#include <hip/hip_runtime.h>

// HeteroRGCN forward, MI355X. Structure (rounds 1-4):
//  - Only h2["target"] matters => layer1 etypes 1,3; layer2 etypes 0,2. x_card/x_ip dead.
//  - Layer1 aggregate-first; layer2+output folded to Wfold=W2@wout (2 cols/node).
//  - bf16 storage + MFMA 16x16x32 for the 128x128 transform; fp32 accumulate.
//  - Single-atomic CSR build (hist rank => atomic-free fill); target side CSR-gather.
//  - Round 5: hist issues all 4 relations' atomics per thread (4x atomic MLP);
//    fill likewise does 4 independent scatters per thread.

#define NT 200000
#define NCARD 100000
#define NIP 100000
#define NE 300000

typedef __attribute__((ext_vector_type(8))) short s8v;   // 8 bf16 (4 VGPRs)
typedef __attribute__((ext_vector_type(4))) float f4v;   // mfma accumulator

__device__ __forceinline__ unsigned short f2b(float f) {
  unsigned u = __float_as_uint(f);
  u = (u + 0x7fff + ((u >> 16) & 1)) >> 16;  // RNE (finite inputs)
  return (unsigned short)u;
}

// ---------------- fused front: hist+rank (4 rel, 4 atomics/thread) | W1^T | Wfold | cvt ----------------

#define NB_HIST 1172   // ceil(NE/256), each thread: 4 independent atomics
#define NB_WT 128
#define NB_CVT 25000

__global__ void front_k(const float* __restrict__ x, const float* __restrict__ w1,
                        const float* __restrict__ w2, const float* __restrict__ b2,
                        const float* __restrict__ wout,
                        const int* __restrict__ d1, const int* __restrict__ d3,
                        const int* __restrict__ d0, const int* __restrict__ d2,
                        int* __restrict__ deg1, int* __restrict__ deg3,
                        int* __restrict__ deg0, int* __restrict__ deg2,
                        int* __restrict__ rk1, int* __restrict__ rk3,
                        int* __restrict__ rk0, int* __restrict__ rk2,
                        unsigned short* __restrict__ xb, unsigned short* __restrict__ wtC,
                        unsigned short* __restrict__ wtI, float* __restrict__ wfC,
                        float* __restrict__ wfI, float* __restrict__ bfC,
                        float* __restrict__ bfI) {
  int bid = blockIdx.x, tid = threadIdx.x;
  if (bid < NB_HIST) {
    int e = bid * 256 + tid;
    if (e < NE) {
      int a1 = d1[e], a3 = d3[e], a0 = d0[e], a2 = d2[e];
      // 4 independent atomics in flight per thread (MLP), results stored coalesced
      int r1 = atomicAdd(&deg1[a1], 1);
      int r3 = atomicAdd(&deg3[a3], 1);
      int r0 = atomicAdd(&deg0[a0], 1);
      int r2 = atomicAdd(&deg2[a2], 1);
      rk1[e] = r1; rk3[e] = r3; rk0[e] = r0; rk2[e] = r2;
    }
  } else if (bid < NB_HIST + NB_WT) {
    int t = (bid - NB_HIST) * 256 + tid;  // 32768
    int r = t >> 14;
    int n = (t >> 7) & 127, k = t & 127;
    const float* src = w1 + (r ? 3 : 1) * 16384;
    unsigned short* dst = r ? wtI : wtC;
    dst[n * 128 + k] = f2b(src[k * 128 + n]);
  } else if (bid == NB_HIST + NB_WT) {
    int k = tid >> 1, o = tid & 1;
    float sC = 0.f, sI = 0.f;
    for (int j = 0; j < 128; j++) {
      float wo = wout[j * 2 + o];
      sC += w2[0 * 16384 + k * 128 + j] * wo;
      sI += w2[2 * 16384 + k * 128 + j] * wo;
    }
    wfC[k * 2 + o] = sC;
    wfI[k * 2 + o] = sI;
    if (tid < 2) {
      float s = 0.f;
      for (int j = 0; j < 128; j++) s += b2[0 * 128 + j] * wout[j * 2 + tid];
      bfC[tid] = s;
    } else if (tid < 4) {
      int oo = tid - 2;
      float s = 0.f;
      for (int j = 0; j < 128; j++) s += b2[2 * 128 + j] * wout[j * 2 + oo];
      bfI[oo] = s;
    }
  } else {
    long i = (long)(bid - (NB_HIST + NB_WT + 1)) * 256 + tid;  // one float4 each
    const long n4 = (long)NT * 128 / 4;
    if (i < n4) {
      float4 v = ((const float4*)x)[i];
      uint2 o;
      o.x = (unsigned)f2b(v.x) | ((unsigned)f2b(v.y) << 16);
      o.y = (unsigned)f2b(v.z) | ((unsigned)f2b(v.w) << 16);
      ((uint2*)xb)[i] = o;
    }
  }
}

// ---------------- scans over degrees -> start offsets (4 relations fused) ----------------

__global__ void scan1q_k(const int* __restrict__ deg1, int* __restrict__ off1,
                         int* __restrict__ bs1, int nb1,
                         const int* __restrict__ deg3, int* __restrict__ off3,
                         int* __restrict__ bs3, int nb3,
                         const int* __restrict__ deg0, int* __restrict__ off0,
                         int* __restrict__ bs0, int nb0,
                         const int* __restrict__ deg2, int* __restrict__ off2,
                         int* __restrict__ bs2) {
  __shared__ int s[256];
  int bid = blockIdx.x;
  const int* deg; int* off; int* bsum; int N; int lb;
  if (bid < nb1) { deg = deg1; off = off1; bsum = bs1; N = NCARD; lb = bid; }
  else if (bid < nb1 + nb3) { deg = deg3; off = off3; bsum = bs3; N = NIP; lb = bid - nb1; }
  else if (bid < nb1 + nb3 + nb0) { deg = deg0; off = off0; bsum = bs0; N = NT; lb = bid - nb1 - nb3; }
  else { deg = deg2; off = off2; bsum = bs2; N = NT; lb = bid - nb1 - nb3 - nb0; }
  int tid = threadIdx.x;
  int i = lb * 256 + tid;
  int v = (i < N) ? deg[i] : 0;
  s[tid] = v;
  __syncthreads();
  for (int o = 1; o < 256; o <<= 1) {
    int t = (tid >= o) ? s[tid - o] : 0;
    __syncthreads();
    s[tid] += t;
    __syncthreads();
  }
  if (i < N) off[i] = s[tid] - v;
  if (tid == 255) bsum[lb] = s[255];
}

__global__ void scan2q_k(int* __restrict__ bs1, int nb1, int* __restrict__ bs3, int nb3,
                         int* __restrict__ bs0, int nb0, int* __restrict__ bs2, int nb2) {
  __shared__ int s[1024];
  int* bs; int nb;
  if (blockIdx.x == 0) { bs = bs1; nb = nb1; }
  else if (blockIdx.x == 1) { bs = bs3; nb = nb3; }
  else if (blockIdx.x == 2) { bs = bs0; nb = nb0; }
  else { bs = bs2; nb = nb2; }
  int t = threadIdx.x;
  int v = (t < nb) ? bs[t] : 0;
  s[t] = v;
  __syncthreads();
  for (int o = 1; o < 1024; o <<= 1) {
    int u = (t >= o) ? s[t - o] : 0;
    __syncthreads();
    s[t] += u;
    __syncthreads();
  }
  if (t < nb) bs[t] = s[t] - v;
}

__global__ void scan3q_k(int* __restrict__ off1, const int* __restrict__ bs1, int nb1,
                         int* __restrict__ off3, const int* __restrict__ bs3, int nb3,
                         int* __restrict__ off0, const int* __restrict__ bs0, int nb0,
                         int* __restrict__ off2, const int* __restrict__ bs2) {
  int bid = blockIdx.x;
  int* off; const int* bsum; int N; int lb;
  if (bid < nb1) { off = off1; bsum = bs1; N = NCARD; lb = bid; }
  else if (bid < nb1 + nb3) { off = off3; bsum = bs3; N = NIP; lb = bid - nb1; }
  else if (bid < nb1 + nb3 + nb0) { off = off0; bsum = bs0; N = NT; lb = bid - nb1 - nb3; }
  else { off = off2; bsum = bs2; N = NT; lb = bid - nb1 - nb3 - nb0; }
  int i = lb * 256 + threadIdx.x;
  if (i < N) off[i] += bsum[lb];
}

// ------- atomic-free CSR fill (rank trick), 4 independent scatters per thread -------

__global__ void fill4_k(const int* __restrict__ s1, const int* __restrict__ d1,
                        const int* __restrict__ rk1, const int* __restrict__ off1,
                        int* __restrict__ csr1,
                        const int* __restrict__ s3, const int* __restrict__ d3,
                        const int* __restrict__ rk3, const int* __restrict__ off3,
                        int* __restrict__ csr3,
                        const int* __restrict__ s0, const int* __restrict__ d0,
                        const int* __restrict__ rk0, const int* __restrict__ off0,
                        int* __restrict__ csr0,
                        const int* __restrict__ s2, const int* __restrict__ d2,
                        const int* __restrict__ rk2, const int* __restrict__ off2,
                        int* __restrict__ csr2) {
  int e = blockIdx.x * 256 + threadIdx.x;
  if (e >= NE) return;
  int a1 = d1[e], a3 = d3[e], a0 = d0[e], a2 = d2[e];
  int o1 = off1[a1], o3 = off3[a3], o0 = off0[a0], o2 = off2[a2];
  csr1[o1 + rk1[e]] = s1[e];
  csr3[o3 + rk3[e]] = s3[e];
  csr0[o0 + rk0[e]] = s0[e];
  csr2[o2 + rk2[e]] = s2[e];
}

// ------- layer1 source aggregation: one wave per dst row -------
// 4 edge-groups x 16 feature-lanes (16B each); shfl_xor reduce across groups.

__global__ void aggf_k(const unsigned short* __restrict__ xb,
                       const int* __restrict__ off1, const int* __restrict__ deg1,
                       const int* __restrict__ csr1, unsigned short* __restrict__ accC,
                       const int* __restrict__ off3, const int* __restrict__ deg3,
                       const int* __restrict__ csr3, unsigned short* __restrict__ accI) {
  int w = (blockIdx.x * 256 + threadIdx.x) >> 6;
  int lane = threadIdx.x & 63;
  if (w >= NCARD + NIP) return;
  const int* off; const int* deg; const int* csr; unsigned short* acc; int row;
  if (w < NCARD) { off = off1; deg = deg1; csr = csr1; acc = accC; row = w; }
  else { off = off3; deg = deg3; csr = csr3; acc = accI; row = w - NCARD; }
  int start = off[row], cnt = deg[row];
  int eg = lane >> 4, fl = lane & 15;
  float a[8] = {0.f, 0.f, 0.f, 0.f, 0.f, 0.f, 0.f, 0.f};
  for (int i = eg; i < cnt; i += 4) {
    int s = csr[start + i];
    uint4 v = *(const uint4*)(xb + (size_t)s * 128 + fl * 8);
    a[0] += __uint_as_float(v.x << 16);
    a[1] += __uint_as_float(v.x & 0xffff0000u);
    a[2] += __uint_as_float(v.y << 16);
    a[3] += __uint_as_float(v.y & 0xffff0000u);
    a[4] += __uint_as_float(v.z << 16);
    a[5] += __uint_as_float(v.z & 0xffff0000u);
    a[6] += __uint_as_float(v.w << 16);
    a[7] += __uint_as_float(v.w & 0xffff0000u);
  }
#pragma unroll
  for (int j = 0; j < 8; j++) {
    a[j] += __shfl_xor(a[j], 16);
    a[j] += __shfl_xor(a[j], 32);
  }
  if (eg == 0) {
    uint4 o;
    o.x = (unsigned)f2b(a[0]) | ((unsigned)f2b(a[1]) << 16);
    o.y = (unsigned)f2b(a[2]) | ((unsigned)f2b(a[3]) << 16);
    o.z = (unsigned)f2b(a[4]) | ((unsigned)f2b(a[5]) << 16);
    o.w = (unsigned)f2b(a[6]) | ((unsigned)f2b(a[7]) << 16);
    *(uint4*)(acc + (size_t)row * 128 + fl * 8) = o;
  }
}

// ------- layer1 transform via MFMA + leaky + fold-to-z epilogue -------
// Per wave: 32 rows x 128 cols, K=128. C/D layout: col=lane&15, row=(lane>>4)*4+reg.
// A layout: A[m=lane&15][k=(lane>>4)*8+j].

__global__ __launch_bounds__(256) void gemm_mfma_k(
    const unsigned short* __restrict__ accC, const unsigned short* __restrict__ accI,
    const unsigned short* __restrict__ wtC, const unsigned short* __restrict__ wtI,
    const float* __restrict__ b1, const int* __restrict__ deg1,
    const int* __restrict__ deg3, const float* __restrict__ wfC,
    const float* __restrict__ wfI, const float* __restrict__ bfC,
    const float* __restrict__ bfI, float* __restrict__ zc, float* __restrict__ zi,
    int gbC) {
  int bid = blockIdx.x;
  const unsigned short* accb; const unsigned short* wt; const float* bias;
  const int* deg; const float* wf; const float* bf; float* zout; int M; int lb;
  if (bid < gbC) {
    accb = accC; wt = wtC; bias = b1 + 128; deg = deg1;
    wf = wfC; bf = bfC; zout = zc; M = NCARD; lb = bid;
  } else {
    accb = accI; wt = wtI; bias = b1 + 384; deg = deg3;
    wf = wfI; bf = bfI; zout = zi; M = NIP; lb = bid - gbC;
  }
  int wave = threadIdx.x >> 6, lane = threadIdx.x & 63;
  int q = lane >> 4, cl = lane & 15;
  int r0w = lb * 128 + wave * 32;

  s8v af[2][4];
#pragma unroll
  for (int rt = 0; rt < 2; rt++)
#pragma unroll
    for (int ks = 0; ks < 4; ks++)
      af[rt][ks] = *(const s8v*)(accb + (size_t)(r0w + rt * 16 + cl) * 128 + ks * 32 + q * 8);

  f4v acc[2][8];
#pragma unroll
  for (int rt = 0; rt < 2; rt++)
#pragma unroll
    for (int nt = 0; nt < 8; nt++) acc[rt][nt] = (f4v){0.f, 0.f, 0.f, 0.f};

#pragma unroll
  for (int nt = 0; nt < 8; nt++) {
#pragma unroll
    for (int ks = 0; ks < 4; ks++) {
      s8v bfr = *(const s8v*)(wt + (size_t)(nt * 16 + cl) * 128 + ks * 32 + q * 8);
      acc[0][nt] = __builtin_amdgcn_mfma_f32_16x16x32_bf16(af[0][ks], bfr, acc[0][nt], 0, 0, 0);
      acc[1][nt] = __builtin_amdgcn_mfma_f32_16x16x32_bf16(af[1][ks], bfr, acc[1][nt], 0, 0, 0);
    }
  }

  float2 wfv[8];
  float b1v[8];
#pragma unroll
  for (int nt = 0; nt < 8; nt++) {
    wfv[nt] = ((const float2*)wf)[nt * 16 + cl];
    b1v[nt] = bias[nt * 16 + cl];
  }
  float2 bf2 = *(const float2*)bf;
#pragma unroll
  for (int rt = 0; rt < 2; rt++) {
#pragma unroll
    for (int reg = 0; reg < 4; reg++) {
      int row = r0w + rt * 16 + q * 4 + reg;
      int d = (row < M) ? deg[row] : 0;
      float sc = (d > 0) ? 1.f / (float)d : 0.f;
      float p0 = 0.f, p1 = 0.f;
#pragma unroll
      for (int nt = 0; nt < 8; nt++) {
        float h = 0.f;
        if (d > 0) {
          h = acc[rt][nt][reg] * sc + b1v[nt];
          h = h > 0.f ? h : 0.01f * h;
        }
        p0 += h * wfv[nt].x;
        p1 += h * wfv[nt].y;
      }
#pragma unroll
      for (int o = 1; o < 16; o <<= 1) {
        p0 += __shfl_xor(p0, o);
        p1 += __shfl_xor(p1, o);
      }
      if (cl == 0 && row < M) {
        ((float2*)zout)[row] = make_float2(p0 + bf2.x, p1 + bf2.y);
      }
    }
  }
}

// ------- target-side: CSR gather of z + mean + softmax (no atomics) -------

__global__ void finalg_k(const float* __restrict__ zc, const float* __restrict__ zi,
                         const int* __restrict__ off0, const int* __restrict__ deg0,
                         const int* __restrict__ csr0, const int* __restrict__ off2,
                         const int* __restrict__ deg2, const int* __restrict__ csr2,
                         const float* __restrict__ bout, float* __restrict__ out) {
  int t = blockIdx.x * 256 + threadIdx.x;
  if (t >= NT) return;
  float l0 = bout[0], l1 = bout[1];
  {
    int d = deg0[t], st = off0[t];
    if (d > 0) {
      float ax = 0.f, ay = 0.f;
      for (int i = 0; i < d; i++) {
        float2 z = ((const float2*)zc)[csr0[st + i]];
        ax += z.x; ay += z.y;
      }
      float inv = 1.f / (float)d;
      l0 += ax * inv; l1 += ay * inv;
    }
  }
  {
    int d = deg2[t], st = off2[t];
    if (d > 0) {
      float ax = 0.f, ay = 0.f;
      for (int i = 0; i < d; i++) {
        float2 z = ((const float2*)zi)[csr2[st + i]];
        ax += z.x; ay += z.y;
      }
      float inv = 1.f / (float)d;
      l0 += ax * inv; l1 += ay * inv;
    }
  }
  float m = fmaxf(l0, l1);
  float e0 = expf(l0 - m), e1 = expf(l1 - m);
  float inv = 1.f / (e0 + e1);
  ((float2*)out)[t] = make_float2(e0 * inv, e1 * inv);
}

// ---------------- launch ----------------

extern "C" void kernel_launch(void* const* d_in, const int* in_sizes, int n_in,
                              void* d_out, int out_size, void* d_ws, size_t ws_size,
                              hipStream_t stream) {
  const float* x_target = (const float*)d_in[0];
  const float* w1 = (const float*)d_in[3];
  const float* b1 = (const float*)d_in[4];
  const float* w2 = (const float*)d_in[5];
  const float* b2 = (const float*)d_in[6];
  const float* wout = (const float*)d_in[7];
  const float* bout = (const float*)d_in[8];
  const int* src0 = (const int*)d_in[9];
  const int* dst0 = (const int*)d_in[10];
  const int* src1 = (const int*)d_in[11];
  const int* dst1 = (const int*)d_in[12];
  const int* src2 = (const int*)d_in[13];
  const int* dst2 = (const int*)d_in[14];
  const int* src3 = (const int*)d_in[15];
  const int* dst3 = (const int*)d_in[16];
  float* out = (float*)d_out;

  char* p = (char*)d_ws;
  auto alloc = [&](size_t bytes) -> char* {
    char* r = p;
    p += (bytes + 255) & ~(size_t)255;
    return r;
  };
  // --- zero region (degree histograms) ---
  int* deg1 = (int*)alloc(NCARD * 4);
  int* deg3 = (int*)alloc(NIP * 4);
  int* deg0 = (int*)alloc(NT * 4);
  int* deg2 = (int*)alloc(NT * 4);
  size_t zero_bytes = (size_t)(p - (char*)d_ws);
  // --- rest ---
  int* rk1 = (int*)alloc(NE * 4);
  int* rk3 = (int*)alloc(NE * 4);
  int* rk0 = (int*)alloc(NE * 4);
  int* rk2 = (int*)alloc(NE * 4);
  int* off1 = (int*)alloc(NCARD * 4);
  int* off3 = (int*)alloc(NIP * 4);
  int* off0 = (int*)alloc(NT * 4);
  int* off2 = (int*)alloc(NT * 4);
  int* bs1 = (int*)alloc(1024 * 4);
  int* bs3 = (int*)alloc(1024 * 4);
  int* bs0 = (int*)alloc(1024 * 4);
  int* bs2 = (int*)alloc(1024 * 4);
  int* csr1 = (int*)alloc(NE * 4);
  int* csr3 = (int*)alloc(NE * 4);
  int* csr0 = (int*)alloc(NE * 4);
  int* csr2 = (int*)alloc(NE * 4);
  unsigned short* xb = (unsigned short*)alloc((size_t)NT * 128 * 2);
  unsigned short* accC = (unsigned short*)alloc((size_t)NCARD * 128 * 2);
  unsigned short* accI = (unsigned short*)alloc((size_t)NIP * 128 * 2);
  alloc(128 * 128 * 2);  // pad: OOB-row A-fragment reads from the last gemm block
  unsigned short* wtC = (unsigned short*)alloc(16384 * 2);
  unsigned short* wtI = (unsigned short*)alloc(16384 * 2);
  float* zc = (float*)alloc((size_t)NCARD * 2 * 4);
  float* zi = (float*)alloc((size_t)NIP * 2 * 4);
  float* wfC = (float*)alloc(256 * 4);
  float* wfI = (float*)alloc(256 * 4);
  float* bfC = (float*)alloc(2 * 4);
  float* bfI = (float*)alloc(2 * 4);

  hipMemsetAsync(d_ws, 0, zero_bytes, stream);

  front_k<<<NB_HIST + NB_WT + 1 + NB_CVT, 256, 0, stream>>>(
      x_target, w1, w2, b2, wout, dst1, dst3, dst0, dst2, deg1, deg3, deg0, deg2,
      rk1, rk3, rk0, rk2, xb, wtC, wtI, wfC, wfI, bfC, bfI);

  int nb1 = (NCARD + 255) / 256, nb3 = (NIP + 255) / 256;
  int nb0 = (NT + 255) / 256, nb2 = (NT + 255) / 256;
  scan1q_k<<<nb1 + nb3 + nb0 + nb2, 256, 0, stream>>>(
      deg1, off1, bs1, nb1, deg3, off3, bs3, nb3, deg0, off0, bs0, nb0, deg2, off2, bs2);
  scan2q_k<<<4, 1024, 0, stream>>>(bs1, nb1, bs3, nb3, bs0, nb0, bs2, nb2);
  scan3q_k<<<nb1 + nb3 + nb0 + nb2, 256, 0, stream>>>(
      off1, bs1, nb1, off3, bs3, nb3, off0, bs0, nb0, off2, bs2);

  fill4_k<<<NB_HIST, 256, 0, stream>>>(
      src1, dst1, rk1, off1, csr1, src3, dst3, rk3, off3, csr3,
      src0, dst0, rk0, off0, csr0, src2, dst2, rk2, off2, csr2);

  aggf_k<<<(NCARD + NIP + 3) / 4, 256, 0, stream>>>(xb, off1, deg1, csr1, accC,
                                                    off3, deg3, csr3, accI);

  int gbC = (NCARD + 127) / 128, gbI = (NIP + 127) / 128;
  gemm_mfma_k<<<gbC + gbI, 256, 0, stream>>>(accC, accI, wtC, wtI, b1, deg1, deg3,
                                             wfC, wfI, bfC, bfI, zc, zi, gbC);

  finalg_k<<<(NT + 255) / 256, 256, 0, stream>>>(zc, zi, off0, deg0, csr0,
                                                 off2, deg2, csr2, bout, out);
}